// Round 1
// baseline (2059.706 us; speedup 1.0000x reference)
//
#include <hip/hip_runtime.h>
#include <math.h>

#define BATCH 128
#define NN    128
#define KK    64

// ---------------------------------------------------------------------------
// helpers
// ---------------------------------------------------------------------------
__device__ __forceinline__ void fma4(float4& a, float s, const float4& v) {
    a.x = fmaf(s, v.x, a.x);
    a.y = fmaf(s, v.y, a.y);
    a.z = fmaf(s, v.z, a.z);
    a.w = fmaf(s, v.w, a.w);
}

// ---------------------------------------------------------------------------
// Kernel 1: out_x[b,m] = x_est[b,m]*w_x[m]
//                      + sum_k (sum_n x_est[b,n]*BB[b,n,m,k] - zB[b,m,k]) * wKL[k,m]
// grid  = (8 m-chunks, 128 batches), block = 256
// thread t: m_local = t>>4 (16 m per block), k4 = t&15 (float4 over k)
// streams BB[b, :, m0:m0+16, :] exactly once, 16B/lane coalesced.
// ---------------------------------------------------------------------------
__global__ __launch_bounds__(256) void einsum_outx_kernel(
    const float* __restrict__ BB, const float* __restrict__ zB,
    const float* __restrict__ xe, const float* __restrict__ wKL,
    const float* __restrict__ wx, float* __restrict__ outx)
{
    const int b  = blockIdx.y;
    const int m0 = blockIdx.x * 16;
    const int t  = threadIdx.x;
    const int ml = t >> 4;   // 0..15
    const int k4 = t & 15;   // float4 index over K: k = 4*k4 .. 4*k4+3

    __shared__ __align__(16) float sx[NN];
    if (t < NN) sx[t] = xe[b * NN + t];
    __syncthreads();

    // BB for this batch, in float4 units: offset(n,m,k4) = (n*128 + m)*16 + k4
    const float4* bb = (const float4*)(BB) + (size_t)b * (NN * NN * (KK / 4));
    const int base = (m0 + ml) * 16 + k4;   // n stride = 128*16 = 2048 float4

    float4 a0 = {0,0,0,0}, a1 = {0,0,0,0}, a2 = {0,0,0,0}, a3 = {0,0,0,0};
    for (int n = 0; n < NN; n += 4) {
        const float4 xv = *(const float4*)&sx[n];
        const float4 v0 = bb[(n + 0) * 2048 + base];
        const float4 v1 = bb[(n + 1) * 2048 + base];
        const float4 v2 = bb[(n + 2) * 2048 + base];
        const float4 v3 = bb[(n + 3) * 2048 + base];
        fma4(a0, xv.x, v0);
        fma4(a1, xv.y, v1);
        fma4(a2, xv.z, v2);
        fma4(a3, xv.w, v3);
    }
    float4 acc;
    acc.x = (a0.x + a1.x) + (a2.x + a3.x);
    acc.y = (a0.y + a1.y) + (a2.y + a3.y);
    acc.z = (a0.z + a1.z) + (a2.z + a3.z);
    acc.w = (a0.w + a1.w) + (a2.w + a3.w);

    const int m = m0 + ml;
    const float4 zv = ((const float4*)zB)[(b * NN + m) * 16 + k4];
    const int k = 4 * k4;
    float contrib = (acc.x - zv.x) * wKL[(k + 0) * NN + m]
                  + (acc.y - zv.y) * wKL[(k + 1) * NN + m]
                  + (acc.z - zv.z) * wKL[(k + 2) * NN + m]
                  + (acc.w - zv.w) * wKL[(k + 3) * NN + m];

    // reduce over the 16 lanes sharing this m (k dimension)
    contrib += __shfl_xor(contrib, 1, 16);
    contrib += __shfl_xor(contrib, 2, 16);
    contrib += __shfl_xor(contrib, 4, 16);
    contrib += __shfl_xor(contrib, 8, 16);

    if (k4 == 0) {
        outx[b * NN + m] = contrib + sx[m] * wx[m];
    }
}

// ---------------------------------------------------------------------------
// Kernel 2: BatchNorm1d (training mode, biased var over batch) + activation.
// grid = 128 (feature n), block = 128 (batch b)
// act_mode 0: relu; 1: soft clip to [-1,1]
// ---------------------------------------------------------------------------
__global__ __launch_bounds__(128) void bn_kernel(
    const float* __restrict__ outx, const float* __restrict__ gamma,
    const float* __restrict__ beta, float* __restrict__ xest,
    float* __restrict__ out_final, int act_mode)
{
    const int n = blockIdx.x;
    const int b = threadIdx.x;

    const float v = outx[b * NN + n];
    float s = v, s2 = v * v;
    for (int off = 32; off; off >>= 1) {
        s  += __shfl_xor(s,  off, 64);
        s2 += __shfl_xor(s2, off, 64);
    }
    __shared__ float ps[2], ps2[2];
    if ((b & 63) == 0) { ps[b >> 6] = s; ps2[b >> 6] = s2; }
    __syncthreads();
    const float sum  = ps[0] + ps[1];
    const float sum2 = ps2[0] + ps2[1];
    const float mean = sum * (1.0f / 128.0f);
    const float var  = sum2 * (1.0f / 128.0f) - mean * mean;

    float y = gamma[n] * (v - mean) * rsqrtf(var + 1e-5f) + beta[n];
    if (act_mode == 0) {
        y = fmaxf(y, 0.0f);
    } else {
        // -1 + relu(y+0.5)/0.5 - relu(y-0.5)/0.5
        y = -1.0f + fmaxf(y + 0.5f, 0.0f) * 2.0f - fmaxf(y - 0.5f, 0.0f) * 2.0f;
    }
    xest[b * NN + n] = y;
    if (out_final) out_final[b * NN + n] = y;
}

// ---------------------------------------------------------------------------
// Kernel 3: loss_l += scale * sum_{b,m,k} (z[b,m,k] - sum_n x_est[b,n]*B[b,n,m,k])^2
// same streaming shape as kernel 1; block reduce + one atomicAdd per block.
// ---------------------------------------------------------------------------
__global__ __launch_bounds__(256) void loss_kernel(
    const float* __restrict__ Bt, const float* __restrict__ z,
    const float* __restrict__ xe, float* __restrict__ loss_out, float scale)
{
    const int b  = blockIdx.y;
    const int m0 = blockIdx.x * 16;
    const int t  = threadIdx.x;
    const int ml = t >> 4;
    const int k4 = t & 15;

    __shared__ __align__(16) float sx[NN];
    if (t < NN) sx[t] = xe[b * NN + t];
    __syncthreads();

    const float4* bb = (const float4*)(Bt) + (size_t)b * (NN * NN * (KK / 4));
    const int base = (m0 + ml) * 16 + k4;

    float4 a0 = {0,0,0,0}, a1 = {0,0,0,0}, a2 = {0,0,0,0}, a3 = {0,0,0,0};
    for (int n = 0; n < NN; n += 4) {
        const float4 xv = *(const float4*)&sx[n];
        const float4 v0 = bb[(n + 0) * 2048 + base];
        const float4 v1 = bb[(n + 1) * 2048 + base];
        const float4 v2 = bb[(n + 2) * 2048 + base];
        const float4 v3 = bb[(n + 3) * 2048 + base];
        fma4(a0, xv.x, v0);
        fma4(a1, xv.y, v1);
        fma4(a2, xv.z, v2);
        fma4(a3, xv.w, v3);
    }
    float4 acc;
    acc.x = (a0.x + a1.x) + (a2.x + a3.x);
    acc.y = (a0.y + a1.y) + (a2.y + a3.y);
    acc.z = (a0.z + a1.z) + (a2.z + a3.z);
    acc.w = (a0.w + a1.w) + (a2.w + a3.w);

    const int m = m0 + ml;
    const float4 zv = ((const float4*)z)[(b * NN + m) * 16 + k4];
    const float dx = zv.x - acc.x;
    const float dy = zv.y - acc.y;
    const float dz = zv.z - acc.z;
    const float dw = zv.w - acc.w;
    float sq = dx * dx + dy * dy + dz * dz + dw * dw;

    for (int off = 32; off; off >>= 1) sq += __shfl_xor(sq, off, 64);
    __shared__ float red[4];
    if ((t & 63) == 0) red[t >> 6] = sq;
    __syncthreads();
    if (t == 0) {
        const float total = (red[0] + red[1]) + (red[2] + red[3]);
        atomicAdd(loss_out, total * scale);
    }
}

// ---------------------------------------------------------------------------
__global__ void zero_losses_kernel(float* __restrict__ p) {
    if (threadIdx.x < 6) p[threadIdx.x] = 0.0f;
}

// ---------------------------------------------------------------------------
extern "C" void kernel_launch(void* const* d_in, const int* in_sizes, int n_in,
                              void* d_out, int out_size, void* d_ws, size_t ws_size,
                              hipStream_t stream)
{
    const float* BB  = (const float*)d_in[0];
    const float* zB  = (const float*)d_in[1];
    // d_in[2] = x : unused by the reference
    const float* z   = (const float*)d_in[3];
    const float* Bt  = (const float*)d_in[4];
    const float* x0  = (const float*)d_in[5];
    const float* wx  = (const float*)d_in[6];
    const float* wKL = (const float*)d_in[7];
    const float* gm  = (const float*)d_in[8];
    const float* bt  = (const float*)d_in[9];

    float* out   = (float*)d_out;               // [0,16384): x_est ; [16384,16390): losses
    float* outx  = (float*)d_ws;                // [BATCH*NN]
    float* xest  = outx + BATCH * NN;           // [BATCH*NN]

    zero_losses_kernel<<<1, 64, 0, stream>>>(out + BATCH * NN);

    const float* xe = x0;
    for (int l = 0; l < 6; ++l) {
        einsum_outx_kernel<<<dim3(8, BATCH), 256, 0, stream>>>(
            BB, zB, xe, wKL + (size_t)l * KK * NN, wx + (size_t)l * NN, outx);

        bn_kernel<<<NN, BATCH, 0, stream>>>(
            outx, gm + (size_t)l * NN, bt + (size_t)l * NN, xest,
            (l == 5) ? out : nullptr, (l < 5) ? 0 : 1);

        const float scale = (float)(10.0 * log((double)(l + 1)) / (128.0 * 128.0));
        loss_kernel<<<dim3(8, BATCH), 256, 0, stream>>>(
            Bt, z, xest, out + BATCH * NN + l, scale);

        xe = xest;
    }
}